// Round 3
// baseline (1630.860 us; speedup 1.0000x reference)
//
#include <hip/hip_runtime.h>
#include <math.h>

#define N_NODES 50000
#define N_EDGES 400000
#define HID 128
#define NH 8
#define HS 16
#define TN 8
#define NR 8
#define TILE 32
#define MAXTILES 1571
#define PERM_SZ (MAXTILES * TILE)
#define SCAN_BLKS ((N_NODES + 255) / 256)   // 196

// ---------- node type sort (counting sort, padded segments of TILE) ----------
__global__ void hist_kernel(const int* __restrict__ ntype, int* __restrict__ cnt) {
    int i = blockIdx.x * 256 + threadIdx.x;
    if (i < N_NODES) atomicAdd(&cnt[ntype[i]], 1);
}
__global__ void scan_kernel(const int* __restrict__ cnt, int* __restrict__ cursor) {
    if (threadIdx.x == 0 && blockIdx.x == 0) {
        int acc = 0;
        for (int t = 0; t < TN; ++t) {
            cursor[t] = acc;
            acc += ((cnt[t] + TILE - 1) / TILE) * TILE;
        }
    }
}
__global__ void scatter_kernel(const int* __restrict__ ntype, int* __restrict__ cursor,
                               int* __restrict__ perm) {
    int i = blockIdx.x * 256 + threadIdx.x;
    if (i < N_NODES) {
        int p = atomicAdd(&cursor[ntype[i]], 1);
        perm[p] = i;
    }
}

// ---------- edge CSR build (sort by dst) ----------
__global__ void hist_dst_kernel(const int* __restrict__ dst, int* __restrict__ cnt) {
    int e = blockIdx.x * 256 + threadIdx.x;
    if (e < N_EDGES) atomicAdd(&cnt[dst[e]], 1);
}
__global__ void scan_block_kernel(const int* __restrict__ cnt, int* __restrict__ excl,
                                  int* __restrict__ bsum) {
    __shared__ int s[256];
    int tid = threadIdx.x;
    int i = blockIdx.x * 256 + tid;
    int v = (i < N_NODES) ? cnt[i] : 0;
    s[tid] = v;
    __syncthreads();
    for (int off = 1; off < 256; off <<= 1) {
        int t = (tid >= off) ? s[tid - off] : 0;
        __syncthreads();
        s[tid] += t;
        __syncthreads();
    }
    if (i < N_NODES) excl[i] = s[tid] - v;
    if (tid == 255) bsum[blockIdx.x] = s[255];
}
__global__ void scan_top_kernel(int* __restrict__ bsum) {
    __shared__ int s[256];
    int tid = threadIdx.x;
    int v = (tid < SCAN_BLKS) ? bsum[tid] : 0;
    s[tid] = v;
    __syncthreads();
    for (int off = 1; off < 256; off <<= 1) {
        int t = (tid >= off) ? s[tid - off] : 0;
        __syncthreads();
        s[tid] += t;
        __syncthreads();
    }
    if (tid < SCAN_BLKS) bsum[tid] = s[tid] - v;   // exclusive
}
__global__ void scan_add_kernel(int* __restrict__ excl, const int* __restrict__ bsum,
                                int* __restrict__ cursor) {
    int i = blockIdx.x * 256 + threadIdx.x;
    if (i < N_NODES) {
        int v = excl[i] + bsum[blockIdx.x];
        excl[i] = v;        // becomes row_ptr
        cursor[i] = v;
    }
}
__global__ void scatter_edge_kernel(const int* __restrict__ src, const int* __restrict__ dst,
                                    const int* __restrict__ etype, int* __restrict__ cursor,
                                    int* __restrict__ esrc, int* __restrict__ eet) {
    int e = blockIdx.x * 256 + threadIdx.x;
    if (e < N_EDGES) {
        int p = atomicAdd(&cursor[dst[e]], 1);
        esrc[p] = src[e];
        eet[p] = etype[e];
    }
}

// ---------- tiled typed GEMM: 32 nodes x 128 outs, 3 matrices (K,Q,V) ----------
__global__ __launch_bounds__(256) void gemm3_kernel(
    const float* __restrict__ x, const int* __restrict__ perm, const int* __restrict__ ntype,
    const float* __restrict__ Wk, const float* __restrict__ Wq, const float* __restrict__ Wv,
    float* __restrict__ K, float* __restrict__ Q, float* __restrict__ V) {
    __shared__ float xs[TILE][HID];
    __shared__ int nodes[TILE];
    int tid = threadIdx.x;
    const int* pp = perm + blockIdx.x * TILE;
    if (tid < TILE) nodes[tid] = pp[tid];
    __syncthreads();
    if (nodes[0] < 0) return;
    int t = ntype[nodes[0]];
#pragma unroll
    for (int c = 0; c < 4; ++c) {
        int v = tid + c * 256;
        int ns = v >> 5, ii = (v & 31) * 4;
        int node = nodes[ns];
        float4 val = (node >= 0) ? *(const float4*)(x + (size_t)node * HID + ii)
                                 : make_float4(0.f, 0.f, 0.f, 0.f);
        *(float4*)(&xs[ns][ii]) = val;
    }
    __syncthreads();
    int og = tid & 31, ng = tid >> 5;
    int j0 = og * 4, n0 = ng * 4;
    const float* wk = Wk + (size_t)t * HID * HID + j0;
    const float* wq = Wq + (size_t)t * HID * HID + j0;
    const float* wv = Wv + (size_t)t * HID * HID + j0;
    float aK[4][4] = {{0}}, aQ[4][4] = {{0}}, aV[4][4] = {{0}};
    for (int i = 0; i < HID; i += 4) {
        float4 xr[4];
#pragma unroll
        for (int nn = 0; nn < 4; ++nn) xr[nn] = *(const float4*)(&xs[n0 + nn][i]);
#pragma unroll
        for (int ii = 0; ii < 4; ++ii) {
            float4 wkv = *(const float4*)(wk + (size_t)(i + ii) * HID);
            float4 wqv = *(const float4*)(wq + (size_t)(i + ii) * HID);
            float4 wvv = *(const float4*)(wv + (size_t)(i + ii) * HID);
#pragma unroll
            for (int nn = 0; nn < 4; ++nn) {
                float xv = ((const float*)&xr[nn])[ii];
                aK[nn][0] = fmaf(xv, wkv.x, aK[nn][0]);
                aK[nn][1] = fmaf(xv, wkv.y, aK[nn][1]);
                aK[nn][2] = fmaf(xv, wkv.z, aK[nn][2]);
                aK[nn][3] = fmaf(xv, wkv.w, aK[nn][3]);
                aQ[nn][0] = fmaf(xv, wqv.x, aQ[nn][0]);
                aQ[nn][1] = fmaf(xv, wqv.y, aQ[nn][1]);
                aQ[nn][2] = fmaf(xv, wqv.z, aQ[nn][2]);
                aQ[nn][3] = fmaf(xv, wqv.w, aQ[nn][3]);
                aV[nn][0] = fmaf(xv, wvv.x, aV[nn][0]);
                aV[nn][1] = fmaf(xv, wvv.y, aV[nn][1]);
                aV[nn][2] = fmaf(xv, wvv.z, aV[nn][2]);
                aV[nn][3] = fmaf(xv, wvv.w, aV[nn][3]);
            }
        }
    }
#pragma unroll
    for (int nn = 0; nn < 4; ++nn) {
        int node = nodes[n0 + nn];
        if (node < 0) continue;
        size_t o = (size_t)node * HID + j0;
        *(float4*)(K + o) = make_float4(aK[nn][0], aK[nn][1], aK[nn][2], aK[nn][3]);
        *(float4*)(Q + o) = make_float4(aQ[nn][0], aQ[nn][1], aQ[nn][2], aQ[nn][3]);
        *(float4*)(V + o) = make_float4(aV[nn][0], aV[nn][1], aV[nn][2], aV[nn][3]);
    }
}

// ---------- tiled GEMM, 1 matrix; perm==null -> identity rows, type 0 ----------
__global__ __launch_bounds__(256) void gemm1_kernel(
    const float* __restrict__ x, const int* __restrict__ perm, const int* __restrict__ ntype,
    const float* __restrict__ W, const float* __restrict__ bias, float* __restrict__ out) {
    __shared__ float xs[TILE][HID];
    __shared__ int nodes[TILE];
    int tid = threadIdx.x;
    if (tid < TILE) {
        int n;
        if (perm) n = perm[blockIdx.x * TILE + tid];
        else { n = blockIdx.x * TILE + tid; if (n >= N_NODES) n = -1; }
        nodes[tid] = n;
    }
    __syncthreads();
    if (nodes[0] < 0) return;
    int t = perm ? ntype[nodes[0]] : 0;
#pragma unroll
    for (int c = 0; c < 4; ++c) {
        int v = tid + c * 256;
        int ns = v >> 5, ii = (v & 31) * 4;
        int node = nodes[ns];
        float4 val = (node >= 0) ? *(const float4*)(x + (size_t)node * HID + ii)
                                 : make_float4(0.f, 0.f, 0.f, 0.f);
        *(float4*)(&xs[ns][ii]) = val;
    }
    __syncthreads();
    int og = tid & 31, ng = tid >> 5;
    int j0 = og * 4, n0 = ng * 4;
    const float* w = W + (size_t)t * HID * HID + j0;
    float acc[4][4] = {{0}};
    for (int i = 0; i < HID; i += 4) {
        float4 xr[4];
#pragma unroll
        for (int nn = 0; nn < 4; ++nn) xr[nn] = *(const float4*)(&xs[n0 + nn][i]);
#pragma unroll
        for (int ii = 0; ii < 4; ++ii) {
            float4 wv = *(const float4*)(w + (size_t)(i + ii) * HID);
#pragma unroll
            for (int nn = 0; nn < 4; ++nn) {
                float xv = ((const float*)&xr[nn])[ii];
                acc[nn][0] = fmaf(xv, wv.x, acc[nn][0]);
                acc[nn][1] = fmaf(xv, wv.y, acc[nn][1]);
                acc[nn][2] = fmaf(xv, wv.z, acc[nn][2]);
                acc[nn][3] = fmaf(xv, wv.w, acc[nn][3]);
            }
        }
    }
    float4 bv = make_float4(0.f, 0.f, 0.f, 0.f);
    if (bias) bv = *(const float4*)(bias + j0);
#pragma unroll
    for (int nn = 0; nn < 4; ++nn) {
        int node = nodes[n0 + nn];
        if (node < 0) continue;
        size_t o = (size_t)node * HID + j0;
        *(float4*)(out + o) = make_float4(acc[nn][0] + bv.x, acc[nn][1] + bv.y,
                                          acc[nn][2] + bv.z, acc[nn][3] + bv.w);
    }
}

// ---------- fused edge pipeline: one wave per dst node, online softmax ----------
// lane = h*8 + og/2 : head h, output dims og, og+1. Also lane covers row
// elements [2*lane, 2*lane+1] for the K/V row gathers (shfl-broadcast to groups).
__global__ __launch_bounds__(256) void fused_edge_kernel(
    const float* __restrict__ K, const float* __restrict__ Q, const float* __restrict__ V,
    const int* __restrict__ row_ptr, const int* __restrict__ deg,
    const int* __restrict__ esrc, const int* __restrict__ eet,
    const float* __restrict__ Watt, const float* __restrict__ Wmsg,
    const float* __restrict__ pri, float* __restrict__ agg) {
    int wave = threadIdx.x >> 6;
    int lane = threadIdx.x & 63;
    int d = blockIdx.x * 4 + wave;
    if (d >= N_NODES) return;
    int h = lane >> 3;
    int og = (lane & 7) * 2;

    float2 qv = *(const float2*)(Q + (size_t)d * HID + h * HS + og);
    int beg = row_ptr[d], dg = deg[d];

    float m = -INFINITY, den = 0.f;
    float accx = 0.f, accy = 0.f;

    for (int e = 0; e < dg; ++e) {
        int s = esrc[beg + e], r = eet[beg + e];
        float2 kv = *(const float2*)(K + (size_t)s * HID + lane * 2);
        float2 vv = *(const float2*)(V + (size_t)s * HID + lane * 2);
        const float* Wa_ = Watt + ((h * NR + r) << 8);
        const float* Wm_ = Wmsg + ((h * NR + r) << 8);

        float kw0 = 0.f, kw1 = 0.f, mg0 = 0.f, mg1 = 0.f;
#pragma unroll
        for (int i = 0; i < HS; ++i) {
            int sl = (h << 3) + (i >> 1);
            float kvi = (i & 1) ? __shfl(kv.y, sl) : __shfl(kv.x, sl);
            float vvi = (i & 1) ? __shfl(vv.y, sl) : __shfl(vv.x, sl);
            float2 wa = *(const float2*)(Wa_ + i * HS + og);
            float2 wm = *(const float2*)(Wm_ + i * HS + og);
            kw0 = fmaf(kvi, wa.x, kw0);
            kw1 = fmaf(kvi, wa.y, kw1);
            mg0 = fmaf(vvi, wm.x, mg0);
            mg1 = fmaf(vvi, wm.y, mg1);
        }
        float a = kw0 * qv.x + kw1 * qv.y;
        a += __shfl_xor(a, 1);
        a += __shfl_xor(a, 2);
        a += __shfl_xor(a, 4);
        a *= pri[h * NR + r] * 0.25f;

        float mn = fmaxf(m, a);
        float scale = (m == -INFINITY) ? 0.f : expf(m - mn);
        float ex = expf(a - mn);
        den = den * scale + ex;
        accx = accx * scale + ex * mg0;
        accy = accy * scale + ex * mg1;
        m = mn;
    }
    float inv = 1.f / (den + 1e-16f);
    *(float2*)(agg + (size_t)d * HID + h * HS + og) = make_float2(accx * inv, accy * inv);
}

// ---------- epilogue: SiLU + gated residual + LayerNorm ----------
__global__ void out_elem_kernel(const float* __restrict__ pre, const float* __restrict__ xin,
                                const int* __restrict__ ntype, const float* __restrict__ skip,
                                const float* __restrict__ g, const float* __restrict__ b,
                                float* __restrict__ xout) {
    int n = blockIdx.x, j = threadIdx.x;
    __shared__ float red[HID];
    int t = ntype[n];
    float acc = pre[n * HID + j];
    float sil = acc / (1.f + expf(-acc));
    float al = 1.f / (1.f + expf(-skip[t]));
    float o = sil * al + xin[n * HID + j] * (1.f - al);
    red[j] = o; __syncthreads();
    for (int s2 = 64; s2; s2 >>= 1) { if (j < s2) red[j] += red[j + s2]; __syncthreads(); }
    float mu = red[0] * (1.f / HID);
    __syncthreads();
    float dv = o - mu;
    red[j] = dv * dv; __syncthreads();
    for (int s2 = 64; s2; s2 >>= 1) { if (j < s2) red[j] += red[j + s2]; __syncthreads(); }
    float var = red[0] * (1.f / HID);
    xout[n * HID + j] = dv * rsqrtf(var + 1e-5f) * g[j] + b[j];
}

extern "C" void kernel_launch(void* const* d_in, const int* in_sizes, int n_in,
                              void* d_out, int out_size, void* d_ws, size_t ws_size,
                              hipStream_t stream) {
    const float* x     = (const float*)d_in[0];
    const int*   eidx  = (const int*)d_in[1];
    const int*   ntype = (const int*)d_in[2];
    const int*   etype = (const int*)d_in[3];
    const float* Wk    = (const float*)d_in[4];
    const float* Wq    = (const float*)d_in[5];
    const float* Wv    = (const float*)d_in[6];
    const float* Wa    = (const float*)d_in[7];
    const float* pri   = (const float*)d_in[8];
    const float* Watt  = (const float*)d_in[9];
    const float* Wmsg  = (const float*)d_in[10];
    const float* skip  = (const float*)d_in[11];
    const float* ln_g  = (const float*)d_in[12];
    const float* ln_b  = (const float*)d_in[13];
    const float* Wff   = (const float*)d_in[14];
    const float* bff   = (const float*)d_in[15];
    const int* src = eidx;
    const int* dst = eidx + N_EDGES;

    char* ws = (char*)d_ws;
    size_t szN = (size_t)N_NODES * HID * sizeof(float);        // 25.6 MB
    float* embA = (float*)(ws);
    float* Kb   = (float*)(ws + szN);
    float* Qb   = (float*)(ws + 2 * szN);                      // Q, then agg, then l1-out
    float* Vb   = (float*)(ws + 3 * szN);                      // V, then pre-activation
    char*  p    = ws + 4 * szN;
    int* perm    = (int*)p;  p += (size_t)PERM_SZ * 4;
    int* cnt     = (int*)p;  p += TN * 4;
    int* cursor  = (int*)p;  p += TN * 4;
    int* row_ptr = (int*)p;  p += (size_t)N_NODES * 4;
    int* cnt_dst = (int*)p;  p += (size_t)N_NODES * 4;
    int* cur_dst = (int*)p;  p += (size_t)N_NODES * 4;
    int* bsum    = (int*)p;  p += 256 * 4;
    int* esrc    = (int*)p;  p += (size_t)N_EDGES * 4;
    int* eet     = (int*)p;  p += (size_t)N_EDGES * 4;

    // node type sort (once)
    hipMemsetAsync(cnt, 0, TN * 4, stream);
    hipMemsetAsync(perm, 0xFF, (size_t)PERM_SZ * 4, stream);
    hist_kernel<<<(N_NODES + 255) / 256, 256, 0, stream>>>(ntype, cnt);
    scan_kernel<<<1, 64, 0, stream>>>(cnt, cursor);
    scatter_kernel<<<(N_NODES + 255) / 256, 256, 0, stream>>>(ntype, cursor, perm);

    // edge CSR by dst (once)
    hipMemsetAsync(cnt_dst, 0, (size_t)N_NODES * 4, stream);
    hist_dst_kernel<<<(N_EDGES + 255) / 256, 256, 0, stream>>>(dst, cnt_dst);
    scan_block_kernel<<<SCAN_BLKS, 256, 0, stream>>>(cnt_dst, row_ptr, bsum);
    scan_top_kernel<<<1, 256, 0, stream>>>(bsum);
    scan_add_kernel<<<SCAN_BLKS, 256, 0, stream>>>(row_ptr, bsum, cur_dst);
    scatter_edge_kernel<<<(N_EDGES + 255) / 256, 256, 0, stream>>>(src, dst, etype, cur_dst,
                                                                   esrc, eet);

    for (int l = 0; l < 2; ++l) {
        const float* xin = l ? embA : x;
        float* xout = l ? Qb : embA;
        const float* Wk_l   = Wk   + (size_t)l * TN * HID * HID;
        const float* Wq_l   = Wq   + (size_t)l * TN * HID * HID;
        const float* Wv_l   = Wv   + (size_t)l * TN * HID * HID;
        const float* Wa_l   = Wa   + (size_t)l * TN * HID * HID;
        const float* Watt_l = Watt + (size_t)l * NH * NR * HS * HS;
        const float* Wmsg_l = Wmsg + (size_t)l * NH * NR * HS * HS;
        const float* pri_l  = pri  + (size_t)l * NH * NR;
        const float* skip_l = skip + (size_t)l * TN;
        const float* g_l    = ln_g + (size_t)l * HID;
        const float* b_l    = ln_b + (size_t)l * HID;

        gemm3_kernel<<<MAXTILES, 256, 0, stream>>>(xin, perm, ntype, Wk_l, Wq_l, Wv_l,
                                                   Kb, Qb, Vb);
        // fused edge pass: agg written into Qb (each wave reads only its own Q row first)
        fused_edge_kernel<<<(N_NODES + 3) / 4, 256, 0, stream>>>(Kb, Qb, Vb, row_ptr, cnt_dst,
                                                                 esrc, eet, Watt_l, Wmsg_l,
                                                                 pri_l, Qb);
        // Wa typed GEMM: agg(Qb) -> pre(Vb)
        gemm1_kernel<<<MAXTILES, 256, 0, stream>>>(Qb, perm, ntype, Wa_l, nullptr, Vb);
        out_elem_kernel<<<N_NODES, HID, 0, stream>>>(Vb, xin, ntype, skip_l, g_l, b_l, xout);
    }
    // final FF: emb(Qb) @ Wff + bff -> d_out
    gemm1_kernel<<<(N_NODES + TILE - 1) / TILE, 256, 0, stream>>>(Qb, nullptr, ntype, Wff,
                                                                  bff, (float*)d_out);
}

// Round 4
// 1619.267 us; speedup vs baseline: 1.0072x; 1.0072x over previous
//
#include <hip/hip_runtime.h>
#include <math.h>

#define N_NODES 50000
#define N_EDGES 400000
#define HID 128
#define NH 8
#define HS 16
#define TN 8
#define NR 8
#define TILE 32
#define MAXTILES 1571
#define PERM_SZ (MAXTILES * TILE)
#define SCAN_BLKS ((N_NODES + 255) / 256)   // 196

// ---------- node type sort (counting sort, padded segments of TILE) ----------
__global__ void hist_kernel(const int* __restrict__ ntype, int* __restrict__ cnt) {
    int i = blockIdx.x * 256 + threadIdx.x;
    if (i < N_NODES) atomicAdd(&cnt[ntype[i]], 1);
}
__global__ void scan_kernel(const int* __restrict__ cnt, int* __restrict__ cursor) {
    if (threadIdx.x == 0 && blockIdx.x == 0) {
        int acc = 0;
        for (int t = 0; t < TN; ++t) {
            cursor[t] = acc;
            acc += ((cnt[t] + TILE - 1) / TILE) * TILE;
        }
    }
}
__global__ void scatter_kernel(const int* __restrict__ ntype, int* __restrict__ cursor,
                               int* __restrict__ perm) {
    int i = blockIdx.x * 256 + threadIdx.x;
    if (i < N_NODES) {
        int p = atomicAdd(&cursor[ntype[i]], 1);
        perm[p] = i;
    }
}

// ---------- edge CSR build (sort by dst) ----------
__global__ void hist_dst_kernel(const int* __restrict__ dst, int* __restrict__ cnt) {
    int e = blockIdx.x * 256 + threadIdx.x;
    if (e < N_EDGES) atomicAdd(&cnt[dst[e]], 1);
}
__global__ void scan_block_kernel(const int* __restrict__ cnt, int* __restrict__ excl,
                                  int* __restrict__ bsum) {
    __shared__ int s[256];
    int tid = threadIdx.x;
    int i = blockIdx.x * 256 + tid;
    int v = (i < N_NODES) ? cnt[i] : 0;
    s[tid] = v;
    __syncthreads();
    for (int off = 1; off < 256; off <<= 1) {
        int t = (tid >= off) ? s[tid - off] : 0;
        __syncthreads();
        s[tid] += t;
        __syncthreads();
    }
    if (i < N_NODES) excl[i] = s[tid] - v;
    if (tid == 255) bsum[blockIdx.x] = s[255];
}
__global__ void scan_top_kernel(int* __restrict__ bsum) {
    __shared__ int s[256];
    int tid = threadIdx.x;
    int v = (tid < SCAN_BLKS) ? bsum[tid] : 0;
    s[tid] = v;
    __syncthreads();
    for (int off = 1; off < 256; off <<= 1) {
        int t = (tid >= off) ? s[tid - off] : 0;
        __syncthreads();
        s[tid] += t;
        __syncthreads();
    }
    if (tid < SCAN_BLKS) bsum[tid] = s[tid] - v;   // exclusive
}
__global__ void scan_add_kernel(int* __restrict__ excl, const int* __restrict__ bsum,
                                int* __restrict__ cursor) {
    int i = blockIdx.x * 256 + threadIdx.x;
    if (i < N_NODES) {
        int v = excl[i] + bsum[blockIdx.x];
        excl[i] = v;        // becomes row_ptr
        cursor[i] = v;
    }
}
// pack src (16 bits) | etype (upper bits)
__global__ void scatter_edge_kernel(const int* __restrict__ src, const int* __restrict__ dst,
                                    const int* __restrict__ etype, int* __restrict__ cursor,
                                    int* __restrict__ epk) {
    int e = blockIdx.x * 256 + threadIdx.x;
    if (e < N_EDGES) {
        int p = atomicAdd(&cursor[dst[e]], 1);
        epk[p] = src[e] | (etype[e] << 16);
    }
}

// ---------- tiled typed GEMM: 32 nodes x 128 outs, 3 matrices (K,Q,V) ----------
__global__ __launch_bounds__(256) void gemm3_kernel(
    const float* __restrict__ x, const int* __restrict__ perm, const int* __restrict__ ntype,
    const float* __restrict__ Wk, const float* __restrict__ Wq, const float* __restrict__ Wv,
    float* __restrict__ K, float* __restrict__ Q, float* __restrict__ V) {
    __shared__ float xs[TILE][HID];
    __shared__ int nodes[TILE];
    int tid = threadIdx.x;
    const int* pp = perm + blockIdx.x * TILE;
    if (tid < TILE) nodes[tid] = pp[tid];
    __syncthreads();
    if (nodes[0] < 0) return;
    int t = ntype[nodes[0]];
#pragma unroll
    for (int c = 0; c < 4; ++c) {
        int v = tid + c * 256;
        int ns = v >> 5, ii = (v & 31) * 4;
        int node = nodes[ns];
        float4 val = (node >= 0) ? *(const float4*)(x + (size_t)node * HID + ii)
                                 : make_float4(0.f, 0.f, 0.f, 0.f);
        *(float4*)(&xs[ns][ii]) = val;
    }
    __syncthreads();
    int og = tid & 31, ng = tid >> 5;
    int j0 = og * 4, n0 = ng * 4;
    const float* wk = Wk + (size_t)t * HID * HID + j0;
    const float* wq = Wq + (size_t)t * HID * HID + j0;
    const float* wv = Wv + (size_t)t * HID * HID + j0;
    float aK[4][4] = {{0}}, aQ[4][4] = {{0}}, aV[4][4] = {{0}};
    for (int i = 0; i < HID; i += 4) {
        float4 xr[4];
#pragma unroll
        for (int nn = 0; nn < 4; ++nn) xr[nn] = *(const float4*)(&xs[n0 + nn][i]);
#pragma unroll
        for (int ii = 0; ii < 4; ++ii) {
            float4 wkv = *(const float4*)(wk + (size_t)(i + ii) * HID);
            float4 wqv = *(const float4*)(wq + (size_t)(i + ii) * HID);
            float4 wvv = *(const float4*)(wv + (size_t)(i + ii) * HID);
#pragma unroll
            for (int nn = 0; nn < 4; ++nn) {
                float xv = ((const float*)&xr[nn])[ii];
                aK[nn][0] = fmaf(xv, wkv.x, aK[nn][0]);
                aK[nn][1] = fmaf(xv, wkv.y, aK[nn][1]);
                aK[nn][2] = fmaf(xv, wkv.z, aK[nn][2]);
                aK[nn][3] = fmaf(xv, wkv.w, aK[nn][3]);
                aQ[nn][0] = fmaf(xv, wqv.x, aQ[nn][0]);
                aQ[nn][1] = fmaf(xv, wqv.y, aQ[nn][1]);
                aQ[nn][2] = fmaf(xv, wqv.z, aQ[nn][2]);
                aQ[nn][3] = fmaf(xv, wqv.w, aQ[nn][3]);
                aV[nn][0] = fmaf(xv, wvv.x, aV[nn][0]);
                aV[nn][1] = fmaf(xv, wvv.y, aV[nn][1]);
                aV[nn][2] = fmaf(xv, wvv.z, aV[nn][2]);
                aV[nn][3] = fmaf(xv, wvv.w, aV[nn][3]);
            }
        }
    }
#pragma unroll
    for (int nn = 0; nn < 4; ++nn) {
        int node = nodes[n0 + nn];
        if (node < 0) continue;
        size_t o = (size_t)node * HID + j0;
        *(float4*)(K + o) = make_float4(aK[nn][0], aK[nn][1], aK[nn][2], aK[nn][3]);
        *(float4*)(Q + o) = make_float4(aQ[nn][0], aQ[nn][1], aQ[nn][2], aQ[nn][3]);
        *(float4*)(V + o) = make_float4(aV[nn][0], aV[nn][1], aV[nn][2], aV[nn][3]);
    }
}

// ---------- tiled GEMM, 1 matrix; perm==null -> identity rows, type 0 ----------
__global__ __launch_bounds__(256) void gemm1_kernel(
    const float* __restrict__ x, const int* __restrict__ perm, const int* __restrict__ ntype,
    const float* __restrict__ W, const float* __restrict__ bias, float* __restrict__ out) {
    __shared__ float xs[TILE][HID];
    __shared__ int nodes[TILE];
    int tid = threadIdx.x;
    if (tid < TILE) {
        int n;
        if (perm) n = perm[blockIdx.x * TILE + tid];
        else { n = blockIdx.x * TILE + tid; if (n >= N_NODES) n = -1; }
        nodes[tid] = n;
    }
    __syncthreads();
    if (nodes[0] < 0) return;
    int t = perm ? ntype[nodes[0]] : 0;
#pragma unroll
    for (int c = 0; c < 4; ++c) {
        int v = tid + c * 256;
        int ns = v >> 5, ii = (v & 31) * 4;
        int node = nodes[ns];
        float4 val = (node >= 0) ? *(const float4*)(x + (size_t)node * HID + ii)
                                 : make_float4(0.f, 0.f, 0.f, 0.f);
        *(float4*)(&xs[ns][ii]) = val;
    }
    __syncthreads();
    int og = tid & 31, ng = tid >> 5;
    int j0 = og * 4, n0 = ng * 4;
    const float* w = W + (size_t)t * HID * HID + j0;
    float acc[4][4] = {{0}};
    for (int i = 0; i < HID; i += 4) {
        float4 xr[4];
#pragma unroll
        for (int nn = 0; nn < 4; ++nn) xr[nn] = *(const float4*)(&xs[n0 + nn][i]);
#pragma unroll
        for (int ii = 0; ii < 4; ++ii) {
            float4 wv = *(const float4*)(w + (size_t)(i + ii) * HID);
#pragma unroll
            for (int nn = 0; nn < 4; ++nn) {
                float xv = ((const float*)&xr[nn])[ii];
                acc[nn][0] = fmaf(xv, wv.x, acc[nn][0]);
                acc[nn][1] = fmaf(xv, wv.y, acc[nn][1]);
                acc[nn][2] = fmaf(xv, wv.z, acc[nn][2]);
                acc[nn][3] = fmaf(xv, wv.w, acc[nn][3]);
            }
        }
    }
    float4 bv = make_float4(0.f, 0.f, 0.f, 0.f);
    if (bias) bv = *(const float4*)(bias + j0);
#pragma unroll
    for (int nn = 0; nn < 4; ++nn) {
        int node = nodes[n0 + nn];
        if (node < 0) continue;
        size_t o = (size_t)node * HID + j0;
        *(float4*)(out + o) = make_float4(acc[nn][0] + bv.x, acc[nn][1] + bv.y,
                                          acc[nn][2] + bv.z, acc[nn][3] + bv.w);
    }
}

// ---------- fused edge pipeline v2: one wave per (dst, head), 4 edges/chunk ----------
// lane = slot*16 + o : slot = edge-in-chunk (0..3), o = head dim (0..15).
// Online softmax merged across the 4 slots per chunk via cross-slot shfl reductions.
__global__ __launch_bounds__(256) void fused_edge_kernel(
    const float* __restrict__ K, const float* __restrict__ Q, const float* __restrict__ V,
    const int* __restrict__ row_ptr, const int* __restrict__ deg,
    const int* __restrict__ epk,
    const float* __restrict__ Watt, const float* __restrict__ Wmsg,
    const float* __restrict__ pri, float* __restrict__ agg) {
    int u = blockIdx.x * 4 + (threadIdx.x >> 6);   // unit = d*NH + h, grid exact
    int lane = threadIdx.x & 63;
    int d = u >> 3, h = u & 7;
    int slot = lane >> 4, o = lane & 15;
    int base = slot << 4;

    float q_o = Q[(size_t)d * HID + h * HS + o];
    int beg = row_ptr[d], dg = deg[d];
    const float* Wa_h = Watt + (size_t)(h * NR) * HS * HS;
    const float* Wm_h = Wmsg + (size_t)(h * NR) * HS * HS;

    float m = -INFINITY, den = 0.f, acc = 0.f;

    for (int c = 0; c < dg; c += 4) {
        int idx = c + slot;
        bool valid = idx < dg;
        int pk = epk[beg + (valid ? idx : dg - 1)];
        int s = pk & 0xFFFF;
        int r = pk >> 16;
        float k_o = K[(size_t)s * HID + h * HS + o];
        float v_o = V[(size_t)s * HID + h * HS + o];
        const float* Wa_ = Wa_h + r * HS * HS;
        const float* Wm_ = Wm_h + r * HS * HS;
        float kw = 0.f, mg = 0.f;
#pragma unroll
        for (int i = 0; i < HS; ++i) {
            float ki = __shfl(k_o, base + i);
            float vi = __shfl(v_o, base + i);
            kw = fmaf(ki, Wa_[i * HS + o], kw);
            mg = fmaf(vi, Wm_[i * HS + o], mg);
        }
        // score for this slot's edge: reduce kw*q over the 16 dims
        float a = kw * q_o;
        a += __shfl_xor(a, 1);
        a += __shfl_xor(a, 2);
        a += __shfl_xor(a, 4);
        a += __shfl_xor(a, 8);
        a *= pri[h * NR + r] * 0.25f;
        if (!valid) a = -INFINITY;
        // chunk max across 4 slots
        float am = fmaxf(a, __shfl_xor(a, 16));
        am = fmaxf(am, __shfl_xor(am, 32));
        float mn = fmaxf(m, am);
        float scale = (m == -INFINITY) ? 0.f : expf(m - mn);
        float ex = expf(a - mn);                   // 0 for invalid slots
        float exs = ex + __shfl_xor(ex, 16);
        exs += __shfl_xor(exs, 32);
        den = den * scale + exs;
        acc = acc * scale + ex * mg;               // per-slot partial, same scale history
        m = mn;
    }
    // combine per-slot partials
    acc += __shfl_xor(acc, 16);
    acc += __shfl_xor(acc, 32);
    if (slot == 0)
        agg[(size_t)d * HID + h * HS + o] = acc / (den + 1e-16f);
}

// ---------- epilogue: SiLU + gated residual + LayerNorm ----------
__global__ void out_elem_kernel(const float* __restrict__ pre, const float* __restrict__ xin,
                                const int* __restrict__ ntype, const float* __restrict__ skip,
                                const float* __restrict__ g, const float* __restrict__ b,
                                float* __restrict__ xout) {
    int n = blockIdx.x, j = threadIdx.x;
    __shared__ float red[HID];
    int t = ntype[n];
    float acc = pre[n * HID + j];
    float sil = acc / (1.f + expf(-acc));
    float al = 1.f / (1.f + expf(-skip[t]));
    float o = sil * al + xin[n * HID + j] * (1.f - al);
    red[j] = o; __syncthreads();
    for (int s2 = 64; s2; s2 >>= 1) { if (j < s2) red[j] += red[j + s2]; __syncthreads(); }
    float mu = red[0] * (1.f / HID);
    __syncthreads();
    float dv = o - mu;
    red[j] = dv * dv; __syncthreads();
    for (int s2 = 64; s2; s2 >>= 1) { if (j < s2) red[j] += red[j + s2]; __syncthreads(); }
    float var = red[0] * (1.f / HID);
    xout[n * HID + j] = dv * rsqrtf(var + 1e-5f) * g[j] + b[j];
}

extern "C" void kernel_launch(void* const* d_in, const int* in_sizes, int n_in,
                              void* d_out, int out_size, void* d_ws, size_t ws_size,
                              hipStream_t stream) {
    const float* x     = (const float*)d_in[0];
    const int*   eidx  = (const int*)d_in[1];
    const int*   ntype = (const int*)d_in[2];
    const int*   etype = (const int*)d_in[3];
    const float* Wk    = (const float*)d_in[4];
    const float* Wq    = (const float*)d_in[5];
    const float* Wv    = (const float*)d_in[6];
    const float* Wa    = (const float*)d_in[7];
    const float* pri   = (const float*)d_in[8];
    const float* Watt  = (const float*)d_in[9];
    const float* Wmsg  = (const float*)d_in[10];
    const float* skip  = (const float*)d_in[11];
    const float* ln_g  = (const float*)d_in[12];
    const float* ln_b  = (const float*)d_in[13];
    const float* Wff   = (const float*)d_in[14];
    const float* bff   = (const float*)d_in[15];
    const int* src = eidx;
    const int* dst = eidx + N_EDGES;

    char* ws = (char*)d_ws;
    size_t szN = (size_t)N_NODES * HID * sizeof(float);        // 25.6 MB
    float* embA = (float*)(ws);
    float* Kb   = (float*)(ws + szN);
    float* Qb   = (float*)(ws + 2 * szN);                      // Q, then agg, then l1-out
    float* Vb   = (float*)(ws + 3 * szN);                      // V, then pre-activation
    char*  p    = ws + 4 * szN;
    int* perm    = (int*)p;  p += (size_t)PERM_SZ * 4;
    int* cnt     = (int*)p;  p += TN * 4;
    int* cursor  = (int*)p;  p += TN * 4;
    int* row_ptr = (int*)p;  p += (size_t)N_NODES * 4;
    int* cnt_dst = (int*)p;  p += (size_t)N_NODES * 4;
    int* cur_dst = (int*)p;  p += (size_t)N_NODES * 4;
    int* bsum    = (int*)p;  p += 256 * 4;
    int* epk     = (int*)p;  p += (size_t)N_EDGES * 4;

    // node type sort (once)
    hipMemsetAsync(cnt, 0, TN * 4, stream);
    hipMemsetAsync(perm, 0xFF, (size_t)PERM_SZ * 4, stream);
    hist_kernel<<<(N_NODES + 255) / 256, 256, 0, stream>>>(ntype, cnt);
    scan_kernel<<<1, 64, 0, stream>>>(cnt, cursor);
    scatter_kernel<<<(N_NODES + 255) / 256, 256, 0, stream>>>(ntype, cursor, perm);

    // edge CSR by dst (once)
    hipMemsetAsync(cnt_dst, 0, (size_t)N_NODES * 4, stream);
    hist_dst_kernel<<<(N_EDGES + 255) / 256, 256, 0, stream>>>(dst, cnt_dst);
    scan_block_kernel<<<SCAN_BLKS, 256, 0, stream>>>(cnt_dst, row_ptr, bsum);
    scan_top_kernel<<<1, 256, 0, stream>>>(bsum);
    scan_add_kernel<<<SCAN_BLKS, 256, 0, stream>>>(row_ptr, bsum, cur_dst);
    scatter_edge_kernel<<<(N_EDGES + 255) / 256, 256, 0, stream>>>(src, dst, etype, cur_dst,
                                                                   epk);

    for (int l = 0; l < 2; ++l) {
        const float* xin = l ? embA : x;
        float* xout = l ? Qb : embA;
        const float* Wk_l   = Wk   + (size_t)l * TN * HID * HID;
        const float* Wq_l   = Wq   + (size_t)l * TN * HID * HID;
        const float* Wv_l   = Wv   + (size_t)l * TN * HID * HID;
        const float* Wa_l   = Wa   + (size_t)l * TN * HID * HID;
        const float* Watt_l = Watt + (size_t)l * NH * NR * HS * HS;
        const float* Wmsg_l = Wmsg + (size_t)l * NH * NR * HS * HS;
        const float* pri_l  = pri  + (size_t)l * NH * NR;
        const float* skip_l = skip + (size_t)l * TN;
        const float* g_l    = ln_g + (size_t)l * HID;
        const float* b_l    = ln_b + (size_t)l * HID;

        gemm3_kernel<<<MAXTILES, 256, 0, stream>>>(xin, perm, ntype, Wk_l, Wq_l, Wv_l,
                                                   Kb, Qb, Vb);
        // fused edge pass: agg written into Qb (each (d,h) unit reads only its own Q slice)
        fused_edge_kernel<<<N_NODES * NH / 4, 256, 0, stream>>>(Kb, Qb, Vb, row_ptr, cnt_dst,
                                                                epk, Watt_l, Wmsg_l,
                                                                pri_l, Qb);
        // Wa typed GEMM: agg(Qb) -> pre(Vb)
        gemm1_kernel<<<MAXTILES, 256, 0, stream>>>(Qb, perm, ntype, Wa_l, nullptr, Vb);
        out_elem_kernel<<<N_NODES, HID, 0, stream>>>(Vb, xin, ntype, skip_l, g_l, b_l, xout);
    }
    // final FF: emb(Qb) @ Wff + bff -> d_out
    gemm1_kernel<<<(N_NODES + TILE - 1) / TILE, 256, 0, stream>>>(Qb, nullptr, ntype, Wff,
                                                                  bff, (float*)d_out);
}